// Round 1
// 772.462 us; speedup vs baseline: 1.0509x; 1.0509x over previous
//
#include <hip/hip_runtime.h>
#include <hip/hip_bf16.h>
#include <stdint.h>
#include <math.h>

#define T_SEQ 2048
#define D_IN  1024
#define H1_N  512

typedef short  short8  __attribute__((ext_vector_type(8)));
typedef __bf16 bf16x8  __attribute__((ext_vector_type(8)));
typedef float  floatx4 __attribute__((ext_vector_type(4)));

#if defined(__HIP_DEVICE_COMPILE__) && __has_builtin(__builtin_amdgcn_global_load_lds)
#define HAS_GLL 1
#endif

__device__ __forceinline__ short f2bf(float f) {
    union { float f; unsigned u; } v; v.f = f;
    unsigned r = v.u + 0x7fffu + ((v.u >> 16) & 1u);   // RNE
    return (short)(r >> 16);
}

// ---------------------------------------------------------------------------
// Prep: W1 [D,H1] fp32 -> W1T [H1][D] bf16(short) via coalesced LDS transpose;
// block 128 computes w_eff = W2@W3 and c_eff = b2.W3 + b3.
// ---------------------------------------------------------------------------
__global__ __launch_bounds__(256)
void prep_kernel(const float* __restrict__ W1, const float* __restrict__ W2,
                 const float* __restrict__ b2, const float* __restrict__ W3,
                 const float* __restrict__ b3, short* __restrict__ W1T,
                 float* __restrict__ weff, float* __restrict__ ceff) {
    const int t = threadIdx.x;
    if (blockIdx.x == 128) {
        for (int h = t; h < H1_N; h += 256) {
            float s = 0.f;
            for (int k = 0; k < 32; ++k) s += W2[h * 32 + k] * W3[k];
            weff[h] = s;
        }
        if (t == 0) {
            float s = 0.f;
            for (int k = 0; k < 32; ++k) s += b2[k] * W3[k];
            *ceff = s + b3[0];
        }
        return;
    }
    __shared__ float tile[64][65];
    const int dx = blockIdx.x >> 3;        // 0..15  -> d0 = dx*64
    const int ny = blockIdx.x & 7;         // 0..7   -> n0 = ny*64
    const int d0 = dx * 64, n0 = ny * 64;
#pragma unroll
    for (int i = 0; i < 16; ++i) {
        int e = i * 256 + t;               // 0..4095
        int r = e >> 6, c = e & 63;
        tile[r][c] = W1[(size_t)(d0 + r) * H1_N + n0 + c];
    }
    __syncthreads();
#pragma unroll
    for (int i = 0; i < 8; ++i) {
        int o = i * 512 + t * 2;           // pairs
        int rr = o >> 6, cc = o & 63;
        unsigned lo = (unsigned short)f2bf(tile[cc][rr]);
        unsigned hi = (unsigned short)f2bf(tile[cc + 1][rr]);
        *(unsigned*)&W1T[(size_t)(n0 + rr) * D_IN + d0 + cc] = lo | (hi << 16);
    }
}

// ---------------------------------------------------------------------------
// Fused GEMM1 + relu + (.w_eff) + sigmoid -> logits[B,T]
// Block: 128 rows x N=512, K-slabs of 64. 2-PHASE PIPELINE (T3-min + T14):
//   - Bs double-buffered (2x64KB), gll for slab k+1 issued BEFORE compute(k)
//   - A tile for slab k+1 prefetched into 16 fp32 regs BEFORE compute(k);
//     convert+ds_write happen AFTER the drain barrier (single As buffer)
// so the barrier drain lands after ~2.5k cycles of MFMA instead of right
// after issue. LDS 146.5KB -> 1 block/CU (8 waves), acc[4][8]=128 VGPR.
// ---------------------------------------------------------------------------
__global__ __launch_bounds__(512, 2)
void gemm_kernel(const float* __restrict__ avf, const int* __restrict__ seq_len,
                 const float* __restrict__ b1, const short* __restrict__ W1T,
                 const float* __restrict__ weff, const float* __restrict__ ceff_p,
                 float* __restrict__ logits) {
    const int b  = blockIdx.y;
    const int t0 = blockIdx.x * 128;
    const int seq = seq_len[b];
    if (t0 >= seq) return;                 // fully-masked tile

    __shared__ short Bs[2][H1_N * 64];     // 2 x 64KB, XOR-swizzled [n][k-chunk]
    __shared__ short As[128 * 72];         // 18KB, rows padded 64->72 elems
    __shared__ float red[128];

    const int t   = threadIdx.x;
    const int w   = t >> 6;                // 0..7
    const int l   = t & 63;
    const int q   = l >> 4;                // quad
    const int m16 = l & 15;
    const int wn  = (w & 3) * 128;         // wave col base
    const int wm  = (w >> 2) * 64;         // wave row base

    if (t < 128) red[t] = 0.f;

    floatx4 acc[4][8];
#pragma unroll
    for (int i = 0; i < 4; ++i)
#pragma unroll
        for (int j = 0; j < 8; ++j) acc[i][j] = (floatx4){0.f, 0.f, 0.f, 0.f};

    const size_t arow = ((size_t)b * T_SEQ + t0) * D_IN;

    // A-slot assignment: two 8-elem slots per thread, fixed for all slabs
    const int am0 = t >> 3, ac0 = t & 7;               // slot j=0: rows 0..63
    const int am1 = (512 + t) >> 3, ac1 = t & 7;       // slot j=1: rows 64..127
    const bool alive0 = (t0 + am0 < seq);
    const bool alive1 = (t0 + am1 < seq);

    float4 apre[2][2];                                 // 16 fp32 prefetch regs

    // ---- issue B gll for slab k0 into Bs[nxt] (swizzled gather) ----
    auto stageB = [&](int k0, int nxt) {
#pragma unroll
        for (int i = 0; i < 8; ++i) {
            int s = w * 512 + i * 64 + l;              // 16B slot id, 0..4095
            int n = s >> 3;
            int c = (s & 7) ^ (n & 7);                 // source chunk (XOR swizzle)
            const short* gsrc = W1T + (size_t)n * D_IN + k0 + c * 8;
#ifdef HAS_GLL
            __builtin_amdgcn_global_load_lds(
                (const __attribute__((address_space(1))) unsigned int*)gsrc,
                (__attribute__((address_space(3))) unsigned int*)((char*)&Bs[nxt][0] + (w * 512 + i * 64) * 16),
                16, 0, 0);
#else
            *(short8*)((char*)&Bs[nxt][0] + (size_t)s * 16) = *(const short8*)gsrc;
#endif
        }
    };

    // ---- issue A global loads for slab k0 into regs (no wait here) ----
    auto loadA = [&](int k0) {
        if (alive0) {
            const float* g = avf + arow + (size_t)am0 * D_IN + k0 + ac0 * 8;
            apre[0][0] = *(const float4*)g;
            apre[0][1] = *(const float4*)(g + 4);
        }
        if (alive1) {
            const float* g = avf + arow + (size_t)am1 * D_IN + k0 + ac1 * 8;
            apre[1][0] = *(const float4*)g;
            apre[1][1] = *(const float4*)(g + 4);
        }
    };

    // ---- convert prefetched regs -> bf16 -> As (post-barrier) ----
    auto writeA = [&]() {
        if (alive0) {
            short8 v;
            v[0] = f2bf(apre[0][0].x); v[1] = f2bf(apre[0][0].y);
            v[2] = f2bf(apre[0][0].z); v[3] = f2bf(apre[0][0].w);
            v[4] = f2bf(apre[0][1].x); v[5] = f2bf(apre[0][1].y);
            v[6] = f2bf(apre[0][1].z); v[7] = f2bf(apre[0][1].w);
            *(short8*)(&As[am0 * 72 + ac0 * 8]) = v;
        }
        if (alive1) {
            short8 v;
            v[0] = f2bf(apre[1][0].x); v[1] = f2bf(apre[1][0].y);
            v[2] = f2bf(apre[1][0].z); v[3] = f2bf(apre[1][0].w);
            v[4] = f2bf(apre[1][1].x); v[5] = f2bf(apre[1][1].y);
            v[6] = f2bf(apre[1][1].z); v[7] = f2bf(apre[1][1].w);
            *(short8*)(&As[am1 * 72 + ac1 * 8]) = v;
        }
    };

    // ---- prologue: stage slab 0 ----
    stageB(0, 0);
    loadA(0);
    writeA();            // compiler inserts vmcnt wait for apre just before use
    __syncthreads();     // drains gll B0 + As writes

    int cur = 0;
    for (int it = 0; it < 16; ++it) {
        // phase 1: issue next slab's loads BEFORE compute (latency hides under MFMA)
        if (it < 15) {
            stageB((it + 1) * 64, cur ^ 1);
            loadA((it + 1) * 64);
        }

        // phase 2: MFMA over current slab (two k-tiles of 32)
#pragma unroll
        for (int kt = 0; kt < 2; ++kt) {
            short8 af[4], bfr[8];
#pragma unroll
            for (int mt = 0; mt < 4; ++mt)
                af[mt] = *(const short8*)(&As[(wm + mt * 16 + m16) * 72 + kt * 32 + q * 8]);
#pragma unroll
            for (int nt = 0; nt < 8; ++nt) {
                int n = wn + nt * 16 + m16;
                int c = (kt * 4 + q) ^ (n & 7);
                bfr[nt] = *(const short8*)((char*)&Bs[cur][0] + (size_t)(n * 8 + c) * 16);
            }
#pragma unroll
            for (int mt = 0; mt < 4; ++mt)
#pragma unroll
                for (int nt = 0; nt < 8; ++nt)
                    acc[mt][nt] = __builtin_amdgcn_mfma_f32_16x16x32_bf16(
                        __builtin_bit_cast(bf16x8, af[mt]),
                        __builtin_bit_cast(bf16x8, bfr[nt]),
                        acc[mt][nt], 0, 0, 0);
        }

        __syncthreads();          // drain: B_next in LDS, apre regs ready, As reads done
        if (it < 15) writeA();    // overwrite As (single buffer) post-barrier
        __syncthreads();
        cur ^= 1;
    }

    // ---- epilogue: logit_row += relu(h + b1) . w_eff, fused per lane ----
    float bv[8], wv[8];
#pragma unroll
    for (int nt = 0; nt < 8; ++nt) {
        int col = wn + nt * 16 + m16;
        bv[nt] = b1[col];
        wv[nt] = weff[col];
    }
#pragma unroll
    for (int mt = 0; mt < 4; ++mt) {
#pragma unroll
        for (int r = 0; r < 4; ++r) {
            float p = 0.f;
#pragma unroll
            for (int nt = 0; nt < 8; ++nt) {
                float h = acc[mt][nt][r] + bv[nt];
                p += fmaxf(h, 0.f) * wv[nt];
            }
            // reduce across the 16 lanes holding different cols of this row
#pragma unroll
            for (int off = 1; off < 16; off <<= 1) p += __shfl_xor(p, off, 64);
            if (m16 == 0) atomicAdd(&red[wm + mt * 16 + q * 4 + r], p);
        }
    }
    __syncthreads();
    if (t < 128) {
        float x = red[t] + ceff_p[0];
        logits[(size_t)b * T_SEQ + t0 + t] = 1.f / (1.f + __expf(-x));
    }
}

// ---------------------------------------------------------------------------
// Top-k per batch via radix-select on positive-float bits (monotone as uint).
// 4x 8-bit digit passes find the exact ks-th largest value (pivot); then
// sum = sum(x > pivot) + (ks - cnt_gt) * pivot.  Values live in registers
// (<= 8 per thread); sentinel 0.0f ranks below all sigmoid outputs (>0).
// ---------------------------------------------------------------------------
__global__ __launch_bounds__(256)
void topk_kernel(const float* __restrict__ logits, const int* __restrict__ seq_len,
                 float* __restrict__ out) {
    __shared__ unsigned hist[256];
    __shared__ unsigned sufA[256], sufB[256];
    __shared__ unsigned sh_sel, sh_want;
    __shared__ float rs[4];
    __shared__ unsigned rc[4];

    const int b = blockIdx.x;
    const int t = threadIdx.x;
    const int seq = seq_len[b];
    const int ks = seq / 16 + 1;           // 2..129, always <= seq
    const float* lg = logits + (size_t)b * T_SEQ;

    float r[8];
#pragma unroll
    for (int j = 0; j < 8; ++j) {
        int i = j * 256 + t;
        r[j] = (i < seq) ? lg[i] : 0.0f;   // sentinel 0 < any sigmoid output
    }

    unsigned prefix = 0;
    unsigned want = (unsigned)ks;
    for (int shift = 24; shift >= 0; shift -= 8) {
        const unsigned maskHi = (shift == 24) ? 0u : (0xFFFFFFFFu << (shift + 8));
        hist[t] = 0;
        __syncthreads();
#pragma unroll
        for (int j = 0; j < 8; ++j) {
            unsigned u = __float_as_uint(r[j]);
            if ((u & maskHi) == (prefix & maskHi))
                atomicAdd(&hist[(u >> shift) & 0xFF], 1u);
        }
        __syncthreads();
        // suffix sums: suf[d] = # candidates with digit >= d
        sufA[t] = hist[t];
        __syncthreads();
        unsigned* src = sufA; unsigned* dst = sufB;
#pragma unroll
        for (int off = 1; off < 256; off <<= 1) {
            dst[t] = src[t] + ((t + off < 256) ? src[t + off] : 0u);
            __syncthreads();
            unsigned* tmp = src; src = dst; dst = tmp;
        }
        unsigned ge = src[t];
        unsigned ge_next = (t < 255) ? src[t + 1] : 0u;
        if (ge >= want && ge_next < want) {      // exactly one thread
            sh_sel = (unsigned)t;
            sh_want = want - ge_next;
        }
        __syncthreads();
        prefix |= sh_sel << shift;
        want = sh_want;
    }

    const float pivot = __uint_as_float(prefix);
    float s = 0.f; unsigned cgt = 0;
#pragma unroll
    for (int j = 0; j < 8; ++j) {
        float x = r[j];
        if (x > pivot) { s += x; cgt++; }
    }
#pragma unroll
    for (int off = 32; off > 0; off >>= 1) {
        s   += __shfl_down(s, off, 64);
        cgt += __shfl_down(cgt, off, 64);
    }
    if ((t & 63) == 0) { rs[t >> 6] = s; rc[t >> 6] = cgt; }
    __syncthreads();
    if (t == 0) {
        float S = rs[0] + rs[1] + rs[2] + rs[3];
        unsigned C = rc[0] + rc[1] + rc[2] + rc[3];
        out[b] = (S + (float)(ks - (int)C) * pivot) / (float)ks;
    }
}

// ---------------------------------------------------------------------------
extern "C" void kernel_launch(void* const* d_in, const int* in_sizes, int n_in,
                              void* d_out, int out_size, void* d_ws, size_t ws_size,
                              hipStream_t stream) {
    const float* avf = (const float*)d_in[0];
    const int*   seq = (const int*)  d_in[1];
    const float* W1  = (const float*)d_in[2];
    const float* b1  = (const float*)d_in[3];
    const float* W2  = (const float*)d_in[4];
    const float* b2  = (const float*)d_in[5];
    const float* W3  = (const float*)d_in[6];
    const float* b3  = (const float*)d_in[7];
    float* out = (float*)d_out;

    // workspace layout
    short* W1T    = (short*)d_ws;                         // 512*1024*2 = 1 MB
    float* weff   = (float*)((char*)d_ws + (1 << 20));    // 512 floats
    float* ceff   = weff + 512;                           // 1 float
    float* logits = weff + 1024;                          // B*T floats (512 KB)

    prep_kernel<<<dim3(129), dim3(256), 0, stream>>>(W1, W2, b2, W3, b3, W1T, weff, ceff);
    gemm_kernel<<<dim3(T_SEQ / 128, 64), dim3(512), 0, stream>>>(avf, seq, b1, W1T, weff, ceff, logits);
    topk_kernel<<<dim3(64), dim3(256), 0, stream>>>(logits, seq, out);
}